// Round 2
// baseline (509.687 us; speedup 1.0000x reference)
//
#include <hip/hip_runtime.h>
#include <hip/hip_bf16.h>

// AngularBasis: real spherical harmonics l=0..7 for N points.
// OUTPUT IS FLOAT32 (harness compares after bf16-rounding both sides).
// Layout: 8 chunks [N, 2l+1] concatenated; chunk l starts at float N*l*l.
//
// v3: occupancy + pipelining.
//  - Rolling 2-row associated-Legendre DP (rows l-1, l-2 only) -> VGPR
//    ~70-90 instead of Pa[8][8]=64 live floats. __launch_bounds__(128,4)
//    caps at 128 VGPR -> >=4 waves/SIMD by registers.
//  - LDS double buffer of one chunk each (2 x 15 x 128 floats = 15.4 KB,
//    was 32.8 KB) -> 8-10 blocks/CU (was 5), 16+ waves/CU.
//  - Pipeline per l: write chunk l into buf[l&1] while copying chunk l-1
//    from buf[(l-1)&1]; one barrier per l. Stores spread across the whole
//    kernel instead of one burst after a single big barrier.
//  - Chunk 0 is the constant Y00 -> stored directly, no LDS.
// Numerics: identical expression trees to v2 (same muls/divides/order);
// exact f32 divides and sincosf kept.
// Roofline (our kernel): 512MB write + 16MB read @ ~6.3 TB/s ~= 84-90 us.

#define BLOCK 128
#define MAXW 15
#define BUFSZ (BLOCK * MAXW)

// (l+m)! / (l-m)! as double (max 14! = 8.7e10, exact in double)
static constexpr double kfac(int l, int m) {
    double f = 1.0;
    for (int k = l - m + 1; k <= l + m; ++k) f *= (double)k;
    return f;
}

__global__ __launch_bounds__(BLOCK, 4) void sph_harm_f32(
    const float* __restrict__ ct, const float* __restrict__ ph,
    float* __restrict__ out, int N)
{
    __shared__ __align__(16) float buf[2][BUFSZ];  // 15360 B

    const int tid = threadIdx.x;
    const int bp0 = blockIdx.x * BLOCK;
    const int P_blk = min(BLOCK, N - bp0);  // N=2M, BLOCK=128 -> always 128
    const bool full = (P_blk == BLOCK);
    const bool act = (tid < P_blk);

    const int n = bp0 + (act ? tid : 0);
    const float x = ct[n];
    const float p = ph[n];
    float s2 = 1.0f - x * x;
    s2 = s2 < 0.0f ? 0.0f : s2;
    const float st = sqrtf(s2);  // sin(theta) >= 0

    // ---- chunk 0: constant Y00 = sqrt(1/4pi), no LDS needed ----
    const float Y00 = 0.28209479177387814f;
    if (full) {
        if (tid < BLOCK / 4) {
            float4 v; v.x = Y00; v.y = Y00; v.z = Y00; v.w = Y00;
            reinterpret_cast<float4*>(out + bp0)[tid] = v;
        }
    } else {
        for (int e = tid; e < P_blk; e += BLOCK) out[bp0 + e] = Y00;
    }

    // ---- azimuthal terms ----
    float s1, c1;
    sincosf(p, &s1, &c1);
    float cm[8], sm[8];
    cm[0] = 1.0f; sm[0] = 0.0f;
#pragma unroll
    for (int m = 1; m <= 7; ++m) {
        cm[m] = cm[m - 1] * c1 - sm[m - 1] * s1;
        sm[m] = sm[m - 1] * c1 + cm[m - 1] * s1;
    }

    // ---- rolling 2-row Legendre DP + per-chunk pipelined writeback ----
    const double INV4PI = 0.07957747154594767;  // 1/(4*pi)
    const float SQRT2 = 1.4142135623730951f;

    float pp[8], pr[8], cur[8];  // rows l-2, l-1, l (indexed by m)
    pr[0] = 1.0f;                // row 0: P_0^0 = 1

#pragma unroll
    for (int l = 1; l <= 7; ++l) {
        const int w = 2 * l + 1;

        // Row l from rows l-1 / l-2 (identical expressions to reference):
        //   m <= l-2: (2l-1) x P_{l-1}^m - (l+m-1) P_{l-2}^m, / (l-m)
        //   m == l-1: (2m+1) x P_m^m evaluated at m=l-1 -> (2l-1) x pr[l-1]
        //   m == l  : -(2m-1) st P_{m-1}^{m-1} at m=l -> -(2l-1) st pr[l-1]
#pragma unroll
        for (int m = 0; m <= l - 2; ++m)
            cur[m] = ((float)(2 * l - 1) * x * pr[m]
                      - (float)(l + m - 1) * pp[m]) / (float)(l - m);
        cur[l - 1] = (float)(2 * l - 1) * x * pr[l - 1];
        cur[l]     = (float)(-(2 * l - 1)) * st * pr[l - 1];

        // Emit chunk l values into buf[l&1], compact [point][w] layout.
        // Stride w is odd -> lane bank = (tid*w+j)%32 bijective over
        // tid mod 32 -> 2 lanes/bank, conflict-free.
        if (act) {
            float* b = &buf[l & 1][tid * w];
            const float K0 = sqrtf((float)((double)(2 * l + 1) * INV4PI));
            b[l] = K0 * cur[0];  // m = 0 at column l
#pragma unroll
            for (int m = 1; m <= l; ++m) {
                const float Km = sqrtf(
                    (float)((double)(2 * l + 1) * INV4PI / kfac(l, m)));
                const float base = SQRT2 * Km * cur[m];
                b[l - m] = base * sm[m];  // m<0 column (sin)
                b[l + m] = base * cm[m];  // m>0 column (cos)
            }
        }

        // Copy out chunk l-1 (written last iteration into buf[(l-1)&1];
        // the barrier at the end of iteration l-1 made it visible).
        if (l >= 2) {
            const int lc = l - 1, wc = 2 * lc + 1;
            const float* sb = buf[lc & 1];
            float* dst = out + (size_t)N * (size_t)(lc * lc)
                         + (size_t)bp0 * (size_t)wc;
            if (full) {
                const float4* s4 = reinterpret_cast<const float4*>(sb);
                float4* d4 = reinterpret_cast<float4*>(dst);
                const int cnt4 = 32 * wc;
#pragma unroll
                for (int k = 0; k * BLOCK < cnt4; ++k) {
                    const int e = tid + k * BLOCK;
                    if ((k + 1) * BLOCK <= cnt4 || e < cnt4) d4[e] = s4[e];
                }
            } else {
                const int cnt = P_blk * wc;
                for (int e = tid; e < cnt; e += BLOCK) dst[e] = sb[e];
            }
        }

        __syncthreads();

        // Shift rows (fully unrolled -> pure register renaming).
#pragma unroll
        for (int m = 0; m <= l - 1; ++m) pp[m] = pr[m];
#pragma unroll
        for (int m = 0; m <= l; ++m) pr[m] = cur[m];
    }

    // ---- final copy: chunk 7 from buf[1] ----
    {
        const int lc = 7, wc = 15;
        const float* sb = buf[lc & 1];
        float* dst = out + (size_t)N * (size_t)(lc * lc)
                     + (size_t)bp0 * (size_t)wc;
        if (full) {
            const float4* s4 = reinterpret_cast<const float4*>(sb);
            float4* d4 = reinterpret_cast<float4*>(dst);
            const int cnt4 = 32 * wc;  // 480
#pragma unroll
            for (int k = 0; k * BLOCK < cnt4; ++k) {
                const int e = tid + k * BLOCK;
                if ((k + 1) * BLOCK <= cnt4 || e < cnt4) d4[e] = s4[e];
            }
        } else {
            const int cnt = P_blk * wc;
            for (int e = tid; e < cnt; e += BLOCK) dst[e] = sb[e];
        }
    }
}

extern "C" void kernel_launch(void* const* d_in, const int* in_sizes, int n_in,
                              void* d_out, int out_size, void* d_ws, size_t ws_size,
                              hipStream_t stream) {
    const float* ct = (const float*)d_in[0];
    const float* ph = (const float*)d_in[1];
    // d_in[2] is l_max (==7), fixed at compile time.
    float* out = (float*)d_out;
    const int N = in_sizes[0];
    const int blocks = (N + BLOCK - 1) / BLOCK;
    hipLaunchKernelGGL(sph_harm_f32, dim3(blocks), dim3(BLOCK), 0, stream,
                       ct, ph, out, N);
}